// Round 8
// baseline (3977.430 us; speedup 1.0000x reference)
//
#include <hip/hip_runtime.h>
#include <math.h>

#define NGROUP 4
#define BATCH  4096
#define TSTEPS 128

// ---------------- workspace layout (float offsets) ----------------
#define WI0T_OFF 0               // 4*48*64*4  = 49152  : Wi0t[g][k][u][gate]
#define WH0T_OFF 49152           // 4*64*64*4  = 65536  : Wh0t[g][k][u][gate]
#define B0T_OFF  114688          // 4*64*4     = 1024   : b0t[g][u][gate]
#define KAL_OFF  115712          // 4*128*48   = 24576  : per (g,t): K[24], Sinv[16], logdet
#define LL_OFF   147456          // 4*128*4096 = 2097152
#define XN_OFF   (147456 + 2097152)   // 4*128*4096*6 = 12582912

// ---------------- LDS layout (float offsets) ----------------
#define LWH0   0                 // 16384 : [k64][u64][gate4]
#define LB0    16384             // 256   : [u][gate4]
#define LWE1   16640             // 912   : [k19][u48]
#define LBE1   17552             // 48
#define LWE2   17600             // 2304  : [k48][u48]
#define LBE2   19904             // 48
#define LWI1   19952             // 1024  : [k64][q16]
#define LWH1   20976             // 64    : [j4][q16]
#define LB1    21040             // 16
#define LGRP   21056             // 8 groups * GRP_SZ
// per chain-group: h0buf[2][64][8]=1024 | bufF 152 | bufE1 384 | bufE2 384 | h1b[2 waves][32]=64
#define GRP_SZ 2008
#define SMEM_FLOATS (21056 + 8*GRP_SZ)   // 37120 floats = 148480 bytes

__device__ __forceinline__ float fast_sig(float x) {
    return __builtin_amdgcn_rcpf(1.0f + __expf(-x));
}
__device__ __forceinline__ float fast_tanh(float x) {
    float ax = fabsf(x);
    float t  = __expf(-2.0f * ax);
    float r  = (1.0f - t) * __builtin_amdgcn_rcpf(1.0f + t);
    return copysignf(r, x);
}

// ============ prep 1: transpose LSTM0 weights into [k][u][gate4] ============
__global__ void nkf_prep_tr(const float* __restrict__ Wi0, const float* __restrict__ Wh0,
                            const float* __restrict__ b0, float* __restrict__ ws) {
    int idx = blockIdx.x * 256 + threadIdx.x;
    if (idx < 49152) {
        int g = idx / 12288, r2 = idx % 12288;
        int k = r2 >> 8, u = (r2 & 255) >> 2, s = r2 & 3;
        ws[WI0T_OFF + idx] = Wi0[g * 12288 + k * 256 + s * 64 + u];
    } else if (idx < 49152 + 65536) {
        int j = idx - 49152;
        int g = j / 16384, r2 = j % 16384;
        int k = r2 >> 8, u = (r2 & 255) >> 2, s = r2 & 3;
        ws[WH0T_OFF + j] = Wh0[g * 16384 + k * 256 + s * 64 + u];
    } else if (idx < 49152 + 65536 + 1024) {
        int j = idx - 114688;
        int g = j >> 8, r2 = j & 255;
        int u = r2 >> 2, s = r2 & 3;
        ws[B0T_OFF + j] = b0[g * 256 + s * 64 + u];
    }
}

// ============ prep 2: data-independent Kalman gain sequence ============
__global__ void nkf_prep_kal(const float* __restrict__ Q_log, const float* __restrict__ R_log,
                             float* __restrict__ ws) {
    int g = blockIdx.x * blockDim.x + threadIdx.x;
    if (g >= NGROUP) return;
    float Qd[6], Rd[4];
#pragma unroll
    for (int i = 0; i < 6; i++) Qd[i] = expf(Q_log[g * 6 + i]);
#pragma unroll
    for (int i = 0; i < 4; i++) Rd[i] = expf(R_log[i]);
    float P[6][6];
#pragma unroll
    for (int i = 0; i < 6; i++)
#pragma unroll
        for (int j = 0; j < 6; j++) P[i][j] = (i == j) ? 1000.0f : 0.0f;
    float* ko = ws + KAL_OFF + (size_t)g * (TSTEPS * 48);

#pragma unroll 1
    for (int t = 0; t < TSTEPS; t++) {
        float FP[6][6], Pp[6][6];
#pragma unroll
        for (int i = 0; i < 6; i++)
#pragma unroll
            for (int j = 0; j < 6; j++) FP[i][j] = P[i][j] + ((i < 3) ? P[i + 3][j] : 0.0f);
#pragma unroll
        for (int i = 0; i < 6; i++)
#pragma unroll
            for (int j = 0; j < 6; j++) Pp[i][j] = FP[i][j] + ((j < 3) ? FP[i][j + 3] : 0.0f);
#pragma unroll
        for (int i = 0; i < 6; i++) Pp[i][i] += Qd[i];

        float S[4][4];
#pragma unroll
        for (int i = 0; i < 4; i++)
#pragma unroll
            for (int j = 0; j < 4; j++) S[i][j] = Pp[i][j] + ((i == j) ? Rd[i] : 0.0f);

        float L[4][4];
#pragma unroll
        for (int j = 0; j < 4; j++) {
            float d = S[j][j];
            for (int k = 0; k < j; k++) d -= L[j][k] * L[j][k];
            L[j][j] = sqrtf(d);
            float inv = 1.0f / L[j][j];
            for (int i = j + 1; i < 4; i++) {
                float s2 = S[i][j];
                for (int k = 0; k < j; k++) s2 -= L[i][k] * L[j][k];
                L[i][j] = s2 * inv;
            }
        }
        float logdet = 2.0f * (logf(L[0][0]) + logf(L[1][1]) + logf(L[2][2]) + logf(L[3][3]));

        float Li[4][4];
#pragma unroll
        for (int j = 0; j < 4; j++) {
            Li[j][j] = 1.0f / L[j][j];
            for (int i = j + 1; i < 4; i++) {
                float s2 = 0.0f;
                for (int k = j; k < i; k++) s2 += L[i][k] * Li[k][j];
                Li[i][j] = -s2 / L[i][i];
            }
        }
        float Si[4][4];
#pragma unroll
        for (int i = 0; i < 4; i++)
#pragma unroll
            for (int j = 0; j < 4; j++) {
                float s2 = 0.0f;
                for (int k = (i > j ? i : j); k < 4; k++) s2 += Li[k][i] * Li[k][j];
                Si[i][j] = s2;
            }
        float K[6][4];
#pragma unroll
        for (int i = 0; i < 6; i++)
#pragma unroll
            for (int o = 0; o < 4; o++) {
                float s2 = 0.0f;
                for (int m = 0; m < 4; m++) s2 += Pp[i][m] * Si[m][o];
                K[i][o] = s2;
            }
#pragma unroll
        for (int i = 0; i < 6; i++)
#pragma unroll
            for (int o = 0; o < 4; o++) ko[t * 48 + i * 4 + o] = K[i][o];
#pragma unroll
        for (int i = 0; i < 4; i++)
#pragma unroll
            for (int j = 0; j < 4; j++) ko[t * 48 + 24 + i * 4 + j] = Si[i][j];
        ko[t * 48 + 40] = logdet;

        float Pn[6][6];
#pragma unroll
        for (int i = 0; i < 6; i++)
#pragma unroll
            for (int j = 0; j < 6; j++) {
                float s2 = Pp[i][j];
                for (int m = 0; m < 4; m++) s2 -= K[i][m] * Pp[m][j];
                Pn[i][j] = s2;
            }
#pragma unroll
        for (int i = 0; i < 6; i++)
#pragma unroll
            for (int j = 0; j < 6; j++) P[i][j] = Pn[i][j];
    }
}

// ============ main: 8 chain-groups x 2 unit-half waves; 1024 thr; 4 waves/SIMD ============
__global__ __launch_bounds__(1024, 4) void nkf_main(
    const float* __restrict__ z, const float* __restrict__ x0,
    const float* __restrict__ We1, const float* __restrict__ be1,
    const float* __restrict__ We2, const float* __restrict__ be2,
    const float* __restrict__ Wi1, const float* __restrict__ Wh1,
    const float* __restrict__ b1l, const float* __restrict__ ws,
    float* __restrict__ ll_out, float* __restrict__ xn_out) {
    extern __shared__ float sm[];
    const int tid  = threadIdx.x;
    const int g    = blockIdx.x >> 6;
    const int bblk = blockIdx.x & 63;
    const int w    = tid >> 6;
    const int cg   = w >> 1;        // chain-group 0..7
    const int uh   = w & 1;         // unit-half 0..1
    const int l    = tid & 63;

    {   // cooperative weight staging
        const float* wh0g = ws + WH0T_OFF + g * 16384;
        for (int i = tid; i < 16384; i += 1024) sm[LWH0 + i] = wh0g[i];
        if (tid < 256) sm[LB0 + tid] = ws[B0T_OFF + g * 256 + tid];
        if (tid < 912) sm[LWE1 + tid] = We1[tid];
        if (tid < 48) sm[LBE1 + tid] = be1[tid];
        for (int i = tid; i < 2304; i += 1024) sm[LWE2 + i] = We2[i];
        if (tid < 48) sm[LBE2 + tid] = be2[tid];
        sm[LWI1 + tid] = Wi1[g * 1024 + tid];
        if (tid < 64) sm[LWH1 + tid] = Wh1[g * 64 + tid];
        if (tid < 16) sm[LB1 + tid] = b1l[g * 16 + tid];
    }

    float* grp   = sm + LGRP + cg * GRP_SZ;
    float* h0A   = grp;              // h0buf[0][64][8]
    float* h0B   = grp + 512;        // h0buf[1][64][8]
    float* bufF  = grp + 1024;       // feats [19][8]
    float* bufE1 = grp + 1176;       // e1 [48][8]
    float* bufE2 = grp + 1560;       // e2 [48][8]
    float* h1bw  = grp + 1944 + uh * 32;   // per-wave h1 [4][8]
    {
        if (uh == 0) {               // zero h0buf[0]
            float4 z4 = {0.0f, 0.0f, 0.0f, 0.0f};
            *(float4*)&h0A[l * 8]     = z4;
            *(float4*)&h0A[l * 8 + 4] = z4;
        }
        if (l < 32) h1bw[l] = 0.0f;
    }
    __syncthreads();

    const int c   = l >> 3;          // chain 0..7 (E/LSTM1/Kalman phases)
    const int r   = l & 7;
    const int bq  = bblk * 64 + cg * 8 + c;
    const int u32 = l & 31;          // LSTM0: unit within half
    const int uu  = uh * 32 + u32;   // global unit
    const int ch4 = (l >> 5) * 4;    // LSTM0: chain sub-block base (0 or 4)

    float c0v[4];                    // c-state for (uu, chains ch4..ch4+3)
#pragma unroll
    for (int i = 0; i < 4; i++) c0v[i] = 0.0f;
    float c1u = 0.0f;
    float xr[6] = {0, 0, 0, 0, 0, 0};
    float4 zcur = {0, 0, 0, 0};
    if (r == 0) {
#pragma unroll
        for (int i = 0; i < 6; i++) xr[i] = x0[bq * 6 + i];
        zcur = *(const float4*)(z + (size_t)bq * (TSTEPS * 4));
    }
    const float*  kal  = ws + KAL_OFF + (size_t)g * (TSTEPS * 48);
    const float4* wi0g = (const float4*)(ws + WI0T_OFF) + (size_t)g * 3072;

    for (int t = 0; t < TSTEPS; ++t) {
        float* hcur = (t & 1) ? h0B : h0A;
        float* hnxt = (t & 1) ? h0A : h0B;
        // ---- prefetch next z (r==0 lanes) ----
        float4 znv = {0, 0, 0, 0};
        if (r == 0) {
            int tn = (t + 1 < TSTEPS) ? t + 1 : t;
            znv = *(const float4*)(z + ((size_t)bq * TSTEPS + tn) * 4);
        }
        // ---------- feats -> bufF[k][c] (r==0 lanes; both waves write identical bits) ----------
        if (r == 0) {
            bufF[0 * 8 + c] = zcur.x; bufF[1 * 8 + c] = zcur.y;
            bufF[2 * 8 + c] = zcur.z; bufF[3 * 8 + c] = zcur.w;
#pragma unroll
            for (int i = 0; i < 6; i++) bufF[(4 + i) * 8 + c] = xr[i];
            float i0 = zcur.x - xr[0], i1 = zcur.y - xr[1];
            float i2 = zcur.z - xr[2], i3 = zcur.w - xr[3];
            bufF[10 * 8 + c] = i0; bufF[11 * 8 + c] = i1;
            bufF[12 * 8 + c] = i2; bufF[13 * 8 + c] = i3;
            bufF[14 * 8 + c] = sqrtf(i0 * i0 + i1 * i1 + i2 * i2 + i3 * i3);
            bufF[15 * 8 + c] = sqrtf(xr[0] * xr[0] + xr[1] * xr[1] + xr[2] * xr[2]);
            bufF[16 * 8 + c] = sqrtf(xr[3] * xr[3] + xr[4] * xr[4] + xr[5] * xr[5]);
            bufF[17 * 8 + c] = (float)t * 0.01f;
            bufF[18 * 8 + c] = 1.0f;
        }
        asm volatile("" ::: "memory");
        // ---------- E1: lanes 0..47 (lane = unit), 8 chains -> bufE1 ----------
        if (l < 48) {
            float acc[8];
            float bb = sm[LBE1 + l];
#pragma unroll
            for (int i = 0; i < 8; i++) acc[i] = bb;
#pragma unroll
            for (int k = 0; k < 19; k++) {
                float  wv = sm[LWE1 + k * 48 + l];
                float4 f0 = *(const float4*)&bufF[k * 8];
                float4 f1 = *(const float4*)&bufF[k * 8 + 4];
                acc[0] += wv * f0.x; acc[1] += wv * f0.y; acc[2] += wv * f0.z; acc[3] += wv * f0.w;
                acc[4] += wv * f1.x; acc[5] += wv * f1.y; acc[6] += wv * f1.z; acc[7] += wv * f1.w;
            }
            float4 o0 = {fmaxf(acc[0], 0.0f), fmaxf(acc[1], 0.0f), fmaxf(acc[2], 0.0f), fmaxf(acc[3], 0.0f)};
            float4 o1 = {fmaxf(acc[4], 0.0f), fmaxf(acc[5], 0.0f), fmaxf(acc[6], 0.0f), fmaxf(acc[7], 0.0f)};
            *(float4*)&bufE1[l * 8]     = o0;
            *(float4*)&bufE1[l * 8 + 4] = o1;
        }
        asm volatile("" ::: "memory");
        // ---------- E2: lanes 0..47 -> bufE2 ----------
        if (l < 48) {
            float acc[8];
            float bb = sm[LBE2 + l];
#pragma unroll
            for (int i = 0; i < 8; i++) acc[i] = bb;
#pragma unroll 4
            for (int k = 0; k < 48; k++) {
                float  wv = sm[LWE2 + k * 48 + l];
                float4 f0 = *(const float4*)&bufE1[k * 8];
                float4 f1 = *(const float4*)&bufE1[k * 8 + 4];
                acc[0] += wv * f0.x; acc[1] += wv * f0.y; acc[2] += wv * f0.z; acc[3] += wv * f0.w;
                acc[4] += wv * f1.x; acc[5] += wv * f1.y; acc[6] += wv * f1.z; acc[7] += wv * f1.w;
            }
            float4 o0 = {fmaxf(acc[0], 0.0f), fmaxf(acc[1], 0.0f), fmaxf(acc[2], 0.0f), fmaxf(acc[3], 0.0f)};
            float4 o1 = {fmaxf(acc[4], 0.0f), fmaxf(acc[5], 0.0f), fmaxf(acc[6], 0.0f), fmaxf(acc[7], 0.0f)};
            *(float4*)&bufE2[l * 8]     = o0;
            *(float4*)&bufE2[l * 8 + 4] = o1;
        }
        asm volatile("" ::: "memory");
        // ---------- LSTM0: lane = (unit uu, 4 chains at ch4); per-wave weight stream halved ----------
        float ai[4], af[4], ag[4], ao[4];
        {
            float4 bb = *(const float4*)&sm[LB0 + uu * 4];
#pragma unroll
            for (int i = 0; i < 4; i++) { ai[i] = bb.x; af[i] = bb.y; ag[i] = bb.z; ao[i] = bb.w; }
        }
#pragma unroll 4
        for (int k = 0; k < 48; k++) {
            float4 wv = wi0g[k * 64 + uu];
            float4 ev = *(const float4*)&bufE2[k * 8 + ch4];
            float e[4] = {ev.x, ev.y, ev.z, ev.w};
#pragma unroll
            for (int i = 0; i < 4; i++) {
                ai[i] += wv.x * e[i]; af[i] += wv.y * e[i];
                ag[i] += wv.z * e[i]; ao[i] += wv.w * e[i];
            }
        }
#pragma unroll 4
        for (int k = 0; k < 64; k++) {
            float4 wv = *(const float4*)&sm[LWH0 + (k * 64 + uu) * 4];
            float4 hv = *(const float4*)&hcur[k * 8 + ch4];
            float h[4] = {hv.x, hv.y, hv.z, hv.w};
#pragma unroll
            for (int i = 0; i < 4; i++) {
                ai[i] += wv.x * h[i]; af[i] += wv.y * h[i];
                ag[i] += wv.z * h[i]; ao[i] += wv.w * h[i];
            }
        }
        float hn[4];
#pragma unroll
        for (int i = 0; i < 4; i++) {
            float cn = fast_sig(af[i]) * c0v[i] + fast_sig(ai[i]) * fast_tanh(ag[i]);
            c0v[i] = cn;
            hn[i]  = fast_sig(ao[i]) * fast_tanh(cn);
        }
        {
            float4 o = {hn[0], hn[1], hn[2], hn[3]};
            *(float4*)&hnxt[uu * 8 + ch4] = o;
        }
        __syncthreads();    // h0(t) complete; orders all cross-iteration buffer reuse
        // ---------- LSTM1 (duplicated per wave): lane = (chain c, q0=r, q1=r+8) ----------
        float ga  = sm[LB1 + r];
        float gb2 = sm[LB1 + r + 8];
#pragma unroll 4
        for (int k = 0; k < 64; k++) {
            float hv = hnxt[k * 8 + c];
            ga  += sm[LWI1 + k * 16 + r] * hv;
            gb2 += sm[LWI1 + k * 16 + r + 8] * hv;
        }
#pragma unroll
        for (int j = 0; j < 4; j++) {
            float hv = h1bw[j * 8 + c];
            ga  += sm[LWH1 + j * 16 + r] * hv;
            gb2 += sm[LWH1 + j * 16 + r + 8] * hv;
        }
        float fO = __shfl_xor(ga, 4, 64);
        float oO = __shfl_xor(gb2, 4, 64);
        asm volatile("" ::: "memory");
        if (r < 4) {
            float cn = fast_sig(fO) * c1u + fast_sig(ga) * fast_tanh(gb2);
            c1u = cn;
            h1bw[r * 8 + c] = fast_sig(oO) * fast_tanh(cn);
        }
        asm volatile("" ::: "memory");
        // ---------- Kalman measurement update (r==0 lanes; kt uniform -> s_load) ----------
        if (r == 0) {
            const float* kt = kal + t * 48;
            float logp = h1bw[c];
            float a0v = h1bw[8 + c], a1v = h1bw[16 + c], a2v = h1bw[24 + c];
            float xp0 = xr[0] + xr[3] + 0.5f * a0v;   // DT = 1
            float xp1 = xr[1] + xr[4] + 0.5f * a1v;
            float xp2 = xr[2] + xr[5] + 0.5f * a2v;
            float xp3 = xr[3] + a0v;
            float xp4 = xr[4] + a1v;
            float xp5 = xr[5] + a2v;
            float y0 = zcur.x - xp0, y1 = zcur.y - xp1;
            float y2 = zcur.z - xp2, y3 = zcur.w - xp3;
            float xn0 = xp0 + kt[0]  * y0 + kt[1]  * y1 + kt[2]  * y2 + kt[3]  * y3;
            float xn1 = xp1 + kt[4]  * y0 + kt[5]  * y1 + kt[6]  * y2 + kt[7]  * y3;
            float xn2 = xp2 + kt[8]  * y0 + kt[9]  * y1 + kt[10] * y2 + kt[11] * y3;
            float xn3 = xp3 + kt[12] * y0 + kt[13] * y1 + kt[14] * y2 + kt[15] * y3;
            float xn4 = xp4 + kt[16] * y0 + kt[17] * y1 + kt[18] * y2 + kt[19] * y3;
            float xn5 = xp5 + kt[20] * y0 + kt[21] * y1 + kt[22] * y2 + kt[23] * y3;
            float sy0 = kt[24] * y0 + kt[25] * y1 + kt[26] * y2 + kt[27] * y3;
            float sy1 = kt[28] * y0 + kt[29] * y1 + kt[30] * y2 + kt[31] * y3;
            float sy2 = kt[32] * y0 + kt[33] * y1 + kt[34] * y2 + kt[35] * y3;
            float sy3 = kt[36] * y0 + kt[37] * y1 + kt[38] * y2 + kt[39] * y3;
            float quad = y0 * sy0 + y1 * sy1 + y2 * sy2 + y3 * sy3;
            float llv  = logp - 0.5f * (quad + kt[40]);
            xr[0] = xn0; xr[1] = xn1; xr[2] = xn2;
            xr[3] = xn3; xr[4] = xn4; xr[5] = xn5;
            if (uh == 0) {
                size_t base = ((size_t)(g * TSTEPS + t)) * BATCH + bq;
                ll_out[base] = llv;
                float* xo = xn_out + base * 6;
                xo[0] = xn0; xo[1] = xn1; xo[2] = xn2;
                xo[3] = xn3; xo[4] = xn4; xo[5] = xn5;
            }
        }
        zcur = znv;
    }
}

// ============ argmax over groups + gather output ============
__global__ void nkf_gather(const float* __restrict__ ws, float* __restrict__ out) {
    int idx = blockIdx.x * 256 + threadIdx.x;   // t*BATCH + b
    if (idx >= TSTEPS * BATCH) return;
    const float* llp = ws + LL_OFF;
    float best = llp[idx];
    int   bg   = 0;
#pragma unroll
    for (int g2 = 1; g2 < 4; g2++) {
        float v = llp[(size_t)g2 * (TSTEPS * BATCH) + idx];
        if (v > best) { best = v; bg = g2; }
    }
    const float* xp = ws + XN_OFF + ((size_t)bg * (TSTEPS * BATCH) + idx) * 6;
    float* o = out + (size_t)idx * 6;
#pragma unroll
    for (int i = 0; i < 6; i++) o[i] = xp[i];
}

extern "C" void kernel_launch(void* const* d_in, const int* in_sizes, int n_in,
                              void* d_out, int out_size, void* d_ws, size_t ws_size,
                              hipStream_t stream) {
    const float* z   = (const float*)d_in[0];
    const float* x0  = (const float*)d_in[1];
    const float* We1 = (const float*)d_in[2];
    const float* be1 = (const float*)d_in[3];
    const float* We2 = (const float*)d_in[4];
    const float* be2 = (const float*)d_in[5];
    const float* Wi0 = (const float*)d_in[6];
    const float* Wh0 = (const float*)d_in[7];
    const float* b0  = (const float*)d_in[8];
    const float* Wi1 = (const float*)d_in[9];
    const float* Wh1 = (const float*)d_in[10];
    const float* b1l = (const float*)d_in[11];
    const float* Ql  = (const float*)d_in[12];
    const float* Rl  = (const float*)d_in[13];
    float* ws  = (float*)d_ws;
    float* out = (float*)d_out;

    (void)hipFuncSetAttribute((const void*)nkf_main,
                              hipFuncAttributeMaxDynamicSharedMemorySize, SMEM_FLOATS * 4);

    nkf_prep_tr<<<(115712 + 255) / 256, 256, 0, stream>>>(Wi0, Wh0, b0, ws);
    nkf_prep_kal<<<1, 64, 0, stream>>>(Ql, Rl, ws);
    nkf_main<<<256, 1024, SMEM_FLOATS * 4, stream>>>(z, x0, We1, be1, We2, be2,
                                                     Wi1, Wh1, b1l, ws,
                                                     ws + LL_OFF, ws + XN_OFF);
    nkf_gather<<<2048, 256, 0, stream>>>(ws, out);
}